// Round 3
// baseline (526.403 us; speedup 1.0000x reference)
//
#include <hip/hip_runtime.h>
#include <stdint.h>

// Net_49177375539428: recursive tree-NN scorer, all-fp32. 2-kernel version.
//   k_tree2 : FUSED base + level-parallel tree. 8 blocks x 1024 thr.
//             Phase 0: each block redundantly computes all 128 base rows
//             (16 tiles of 8 nodes, vecs rows staged in LDS) + dscore
//             (same-value multi-writer across blocks, benign).
//             Phases 1-5: children lists, depth via pointer jumping,
//             depth buckets (unchanged from round 2).
//             Main loop: DUAL-NODE GEMV - each wave takes nodes q and q+16
//             of the level: two independent W streams + accumulators force
//             ~2x outstanding loads (round-2 compiler compressed the
//             ping-pong to VGPR=52 / ~74 GB/s/CU; port ceiling ~150).
//             FMA order per node identical to round 2 (bit-exact).
//   k_chain2: FUSED step0 + path chain. 64 blocks (8 graphs x 8 chunks of
//             16 e-rows). Step 0 computed in-block into Vbuf[0] (exactly
//             round-0's k_chain step-0 math), then shared path steps with
//             one W per step reused across 16 e-rows.

#define NND 128
#define DD  128
#define GG  8
#define VD  300
#define EDGEN 128
#define CH2 16         // e-rows per k_chain2 block

typedef unsigned int u32;

#define F_POS  (1<<16)
#define F_PATH (1<<17)

// ---------------- K1: fused base + level-parallel tree ----------------
__global__ void __launch_bounds__(1024, 1) k_tree2(
        const int* __restrict__ data,   const int* __restrict__ graphs,
        const int* __restrict__ edges,  const int* __restrict__ posArr,
        const float* __restrict__ vecs, const float* __restrict__ dw,
        const float* __restrict__ db,   const float* __restrict__ sdw,
        const float* __restrict__ sb,
        const float* __restrict__ EW,   const float* __restrict__ EB,
        float* __restrict__ base, float* __restrict__ dscore,
        float* __restrict__ vposG, float* __restrict__ uG, int* __restrict__ meta)
{
    __shared__ __align__(16) float contrib[NND-1][DD];   // 63.5 KB, nodes 0..126
    __shared__ int par_s[NND], eid_s[NND], flg_s[NND];
    __shared__ int ccnt[NND], cstart[NND], cidx[NND];
    __shared__ int dep[NND], anc[NND], lcnt[NND], lstart[NND], order[NND];
    __shared__ int maxD_s;

    int g = blockIdx.x, t = threadIdx.x;

    // ---- phase 0: base embeddings (redundant per block) + dscore ----
    // rowbuf aliases the contrib area (contrib first written by GEMVs later).
    {
        float* rowbuf = &contrib[0][0];          // 8 rows x 304 floats = 9.7KB
        for (int tile = 0; tile < 16; ++tile){
            for (int i = t; i < 8*75; i += 1024){        // 75 float4 per row
                int r = i / 75, el = i - r*75;
                int nn = tile*8 + r;
                ((float4*)&rowbuf[r*304])[el] =
                    ((const float4*)&vecs[(size_t)data[nn]*VD])[el];
            }
            __syncthreads();
            int r = t >> 7, c = t & 127;
            int nn = tile*8 + r;
            const float* rb = &rowbuf[r*304];
            float a0 = db[c], a1 = 0.f, a2 = 0.f, a3 = 0.f;
            for (int d = 0; d < VD; d += 4){
                a0 = fmaf(rb[d+0], dw[(d+0)*DD + c], a0);
                a1 = fmaf(rb[d+1], dw[(d+1)*DD + c], a1);
                a2 = fmaf(rb[d+2], dw[(d+2)*DD + c], a2);
                a3 = fmaf(rb[d+3], dw[(d+3)*DD + c], a3);
            }
            base[nn*DD + c] = (a0 + a1) + (a2 + a3);
            __syncthreads();                     // rowbuf reused next tile
        }
        // dscore (all blocks write the same value - benign)
        int p = posArr[0];
        float* red = rowbuf;
        if (t < DD) red[t] = base[p*DD + t] * sdw[t];
        __syncthreads();
        for (int o = 64; o > 0; o >>= 1){ if (t < o) red[t] += red[t+o]; __syncthreads(); }
        if (t == 0) dscore[0] = sb[0] + red[0];
        __syncthreads();
    }

    // ---- phase 1: load graph structure ----
    if (t < NND){
        par_s[t] = (t < NND-1) ? (t + graphs[g*NND + t]) : (NND-1);  // root self-parent
        eid_s[t] = edges[t];
        flg_s[t] = 0;
        ccnt[t]  = 0;
        lcnt[t]  = 0;
    }
    if (t == 0) maxD_s = 0;
    __syncthreads();

    // ---- phase 2: child counts, sibling slots, depth init, path walk ----
    int mySlot = 0;
    if (t < NND-1){
        int p = par_s[t];
        atomicAdd(&ccnt[p], 1);
        for (int c = 0; c < t; ++c) mySlot += (par_s[c] == p);  // ascending order
    }
    if (t < NND){
        dep[t] = (t < NND-1) ? 1 : 0;
        anc[t] = par_s[t];
    }
    if (t == 0){
        int p = posArr[0];
        flg_s[p] |= F_POS;
        int c = par_s[p], s = 0;
        for (;;){
            flg_s[c] |= F_PATH | (s << 24);
            meta[g*(NND+1) + 1 + s] = c;
            ++s;
            if (c == NND-1) break;
            c = par_s[c];
        }
        meta[g*(NND+1)] = s;                        // path length L
    }
    __syncthreads();

    // ---- phase 3: child list offsets ----
    if (t < NND){
        int s = 0;
        for (int p = 0; p < t; ++p) s += ccnt[p];
        cstart[t] = s;
    }
    __syncthreads();
    if (t < NND-1) cidx[cstart[par_s[t]] + mySlot] = t;

    // ---- phase 4: depth via pointer jumping ----
    for (int k = 0; k < 7; ++k){
        int d2 = 0, a2 = 0;
        if (t < NND){ d2 = dep[t] + dep[anc[t]]; a2 = anc[anc[t]]; }
        __syncthreads();
        if (t < NND){ dep[t] = d2; anc[t] = a2; }
        __syncthreads();
    }
    if (t < NND) atomicMax(&maxD_s, dep[t]);
    if (t < NND) atomicAdd(&lcnt[dep[t]], 1);
    __syncthreads();

    // ---- phase 5: bucket nodes by depth ----
    if (t < NND){
        int s = 0;
        for (int d2 = 0; d2 < t; ++d2) s += lcnt[d2];
        lstart[t] = s;
    }
    __syncthreads();
    if (t < NND){
        int d2 = dep[t], s = 0;
        for (int c = 0; c < t; ++c) s += (dep[c] == d2);
        order[lstart[d2] + s] = t;
    }
    __syncthreads();

    // ---- main: rounds from deepest depth up to root, 2 nodes per wave ----
    int w = t >> 6, l = t & 63;
    int c0 = 2*l;                       // gather mapping: 2 cols/lane
    int li = l & 31, hl = l >> 5;       // GEMV mapping: 4 cols x half-d
    int c4 = 4*li, dbase = 64*hl;
    int maxD = maxD_s;

    // gather + classify; stage emb in contrib[n] if plain-GEMV node
    auto prep = [&](int n)->bool{
        float2 bse = *(const float2*)&base[n*DD + c0];
        float e0 = bse.x, e1 = bse.y;
        int cs = cstart[n], cc = ccnt[n];
        for (int j = 0; j < cc; ++j){
            int c = cidx[cs + j];
            if (!(flg_s[c] & (F_POS | F_PATH))){
                float2 cv = *(const float2*)&contrib[c][c0];
                e0 += cv.x; e1 += cv.y;
            }
        }
        int f = flg_s[n];
        if (f & F_POS){
            if (cc){ e0 = fmaxf(e0, 0.f); e1 = fmaxf(e1, 0.f); }
            *(float2*)&vposG[g*DD + c0] = make_float2(e0, e1);
            return false;
        }
        if (f & F_PATH){
            int slot = ((u32)f) >> 24;
            *(float2*)&uG[((size_t)g*NND + slot)*DD + c0] = make_float2(e0, e1);  // pre-relu
            return false;
        }
        if (cc){ e0 = fmaxf(e0, 0.f); e1 = fmaxf(e1, 0.f); }
        *(float2*)&contrib[n][c0] = make_float2(e0, e1);       // stage emb
        return true;
    };

    auto gemv1 = [&](int n){
        int e = eid_s[n];
        const float* Wp = EW + (size_t)e*(DD*DD) + (size_t)dbase*DD + c4;
        const float* xr = &contrib[n][dbase];
        float4 A[8], B[8];
        float s0=0.f, s1=0.f, s2=0.f, s3=0.f;
        #define LW(buf, gi) { _Pragma("unroll") \
            for (int j2 = 0; j2 < 8; ++j2) \
                buf[j2] = *(const float4*)&Wp[(size_t)((gi)*8 + j2)*DD]; }
        #define CP(buf, gi) { _Pragma("unroll") \
            for (int j2 = 0; j2 < 8; ++j2){ \
                float x = xr[(gi)*8 + j2]; \
                s0 = fmaf(x, buf[j2].x, s0); s1 = fmaf(x, buf[j2].y, s1); \
                s2 = fmaf(x, buf[j2].z, s2); s3 = fmaf(x, buf[j2].w, s3); } }
        LW(A,0); LW(B,1);
        CP(A,0); LW(A,2);
        CP(B,1); LW(B,3);
        CP(A,2); LW(A,4);
        CP(B,3); LW(B,5);
        CP(A,4); LW(A,6);
        CP(B,5); LW(B,7);
        CP(A,6);
        CP(B,7);
        #undef LW
        #undef CP
        s0 += __shfl_xor(s0, 32); s1 += __shfl_xor(s1, 32);
        s2 += __shfl_xor(s2, 32); s3 += __shfl_xor(s3, 32);
        if (hl == 0){
            float4 bb = *(const float4*)&EB[(size_t)e*DD + c4];
            *(float4*)&contrib[n][c4] =
                make_float4(s0 + bb.x, s1 + bb.y, s2 + bb.z, s3 + bb.w);
        }
    };

    auto gemv2 = [&](int n1, int n2){
        int ea = eid_s[n1], eb = eid_s[n2];
        const float* W1 = EW + (size_t)ea*(DD*DD) + (size_t)dbase*DD + c4;
        const float* W2 = EW + (size_t)eb*(DD*DD) + (size_t)dbase*DD + c4;
        const float* x1 = &contrib[n1][dbase];
        const float* x2 = &contrib[n2][dbase];
        float4 A[8], B[8];
        float a0=0.f,a1=0.f,a2=0.f,a3=0.f, b0=0.f,b1=0.f,b2=0.f,b3=0.f;
        #define LW1(gi) { _Pragma("unroll") \
            for (int j2 = 0; j2 < 8; ++j2) \
                A[j2] = *(const float4*)&W1[(size_t)((gi)*8 + j2)*DD]; }
        #define LW2(gi) { _Pragma("unroll") \
            for (int j2 = 0; j2 < 8; ++j2) \
                B[j2] = *(const float4*)&W2[(size_t)((gi)*8 + j2)*DD]; }
        #define CP1(gi) { _Pragma("unroll") \
            for (int j2 = 0; j2 < 8; ++j2){ \
                float x = x1[(gi)*8 + j2]; \
                a0 = fmaf(x, A[j2].x, a0); a1 = fmaf(x, A[j2].y, a1); \
                a2 = fmaf(x, A[j2].z, a2); a3 = fmaf(x, A[j2].w, a3); } }
        #define CP2(gi) { _Pragma("unroll") \
            for (int j2 = 0; j2 < 8; ++j2){ \
                float x = x2[(gi)*8 + j2]; \
                b0 = fmaf(x, B[j2].x, b0); b1 = fmaf(x, B[j2].y, b1); \
                b2 = fmaf(x, B[j2].z, b2); b3 = fmaf(x, B[j2].w, b3); } }
        LW1(0); LW2(0);
        CP1(0); LW1(1);
        CP2(0); LW2(1);
        CP1(1); LW1(2);
        CP2(1); LW2(2);
        CP1(2); LW1(3);
        CP2(2); LW2(3);
        CP1(3); LW1(4);
        CP2(3); LW2(4);
        CP1(4); LW1(5);
        CP2(4); LW2(5);
        CP1(5); LW1(6);
        CP2(5); LW2(6);
        CP1(6); LW1(7);
        CP2(6); LW2(7);
        CP1(7);
        CP2(7);
        #undef LW1
        #undef LW2
        #undef CP1
        #undef CP2
        a0 += __shfl_xor(a0, 32); a1 += __shfl_xor(a1, 32);
        a2 += __shfl_xor(a2, 32); a3 += __shfl_xor(a3, 32);
        b0 += __shfl_xor(b0, 32); b1 += __shfl_xor(b1, 32);
        b2 += __shfl_xor(b2, 32); b3 += __shfl_xor(b3, 32);
        if (hl == 0){
            float4 ba = *(const float4*)&EB[(size_t)ea*DD + c4];
            float4 bb = *(const float4*)&EB[(size_t)eb*DD + c4];
            *(float4*)&contrib[n1][c4] =
                make_float4(a0 + ba.x, a1 + ba.y, a2 + ba.z, a3 + ba.w);
            *(float4*)&contrib[n2][c4] =
                make_float4(b0 + bb.x, b1 + bb.y, b2 + bb.z, b3 + bb.w);
        }
    };

    for (int d = maxD; d >= 0; --d){
        int lo = lstart[d], cnt = lcnt[d];
        for (int q = w; q < cnt; q += 32){
            int n1 = order[lo + q];
            int n2 = (q + 16 < cnt) ? order[lo + q + 16] : -1;
            bool p1 = prep(n1);
            bool p2 = (n2 >= 0) ? prep(n2) : false;
            asm volatile("s_waitcnt lgkmcnt(0)" ::: "memory");   // staged emb RAW
            if (p1 && p2)      gemv2(n1, n2);
            else { if (p1) gemv1(n1);
                   if (p2) gemv1(n2); }
        }
        __syncthreads();
    }
}

// ---------------- K2: fused step0 + path chains ----------------
__global__ void __launch_bounds__(256, 1) k_chain2(
        const int* __restrict__ edges,
        const float* __restrict__ EW, const float* __restrict__ EB,
        const float* __restrict__ SEW,
        const float* __restrict__ vposG, const float* __restrict__ uG,
        const int* __restrict__ meta, const float* __restrict__ dscore,
        float* __restrict__ outp)
{
    __shared__ __align__(16) float Vbuf[2][CH2][DD];
    __shared__ float red[CH2][4];
    int g = blockIdx.x >> 3, chunk = blockIdx.x & 7;
    int t = threadIdx.x, l = t & 63, w = t >> 6;
    int k4 = w*8 + (l & 7);
    int d0 = (l >> 3) * 16;
    bool owner = ((l >> 3) == 0);
    int eBase = chunk * CH2;
    int L = meta[g*(NND+1)];

    // vpos slice (post-relu, from k_tree2) for this lane's d-range
    float vpf[16];
    #pragma unroll
    for (int j = 0; j < 4; ++j){
        float4 x = *(const float4*)&vposG[g*DD + d0 + 4*j];
        vpf[4*j+0]=x.x; vpf[4*j+1]=x.y; vpf[4*j+2]=x.z; vpf[4*j+3]=x.w;
    }
    float4 u0 = *(const float4*)&uG[(size_t)g*NND*DD + 4*k4];

    // ---- step 0 (in-block): per-e weights W[e] ----
    #pragma unroll 2
    for (int p = 0; p < CH2; ++p){
        int e = eBase + p;
        const float* Wp = EW + (size_t)e*(DD*DD) + (size_t)d0*DD + 4*k4;
        float s0=0.f, s1=0.f, s2=0.f, s3=0.f;
        #pragma unroll
        for (int d = 0; d < 16; ++d){
            float4 wv = *(const float4*)&Wp[d*DD];
            s0 = fmaf(vpf[d], wv.x, s0);
            s1 = fmaf(vpf[d], wv.y, s1);
            s2 = fmaf(vpf[d], wv.z, s2);
            s3 = fmaf(vpf[d], wv.w, s3);
        }
        #pragma unroll
        for (int m = 8; m <= 32; m <<= 1){
            s0 += __shfl_xor(s0, m); s1 += __shfl_xor(s1, m);
            s2 += __shfl_xor(s2, m); s3 += __shfl_xor(s3, m);
        }
        if (owner){
            float4 bb = *(const float4*)&EB[(size_t)e*DD + 4*k4];
            float4 r;
            r.x = fmaxf(u0.x + s0 + bb.x, 0.f);
            r.y = fmaxf(u0.y + s1 + bb.y, 0.f);
            r.z = fmaxf(u0.z + s2 + bb.z, 0.f);
            r.w = fmaxf(u0.w + s3 + bb.w, 0.f);
            *(float4*)&Vbuf[0][p][4*k4] = r;
        }
    }
    __syncthreads();

    // ---- shared steps 1..L-1: one W per step, reused across CH2 e-rows ----
    int cur = 0;
    for (int s = 1; s < L; ++s){
        int pn = meta[g*(NND+1) + s];           // path[s-1]
        int ej = edges[pn];
        const float* Wp = EW + (size_t)ej*(DD*DD) + (size_t)d0*DD + 4*k4;
        float4 wr[16];
        #pragma unroll
        for (int d = 0; d < 16; ++d) wr[d] = *(const float4*)&Wp[d*DD];
        float4 us = *(const float4*)&uG[((size_t)g*NND + s)*DD + 4*k4];
        float4 bb = *(const float4*)&EB[(size_t)ej*DD + 4*k4];
        #pragma unroll 4
        for (int p = 0; p < CH2; ++p){
            float ev[16];
            #pragma unroll
            for (int j = 0; j < 4; ++j){
                float4 x = *(const float4*)&Vbuf[cur][p][d0 + 4*j];
                ev[4*j+0]=x.x; ev[4*j+1]=x.y; ev[4*j+2]=x.z; ev[4*j+3]=x.w;
            }
            float s0=0.f, s1=0.f, s2=0.f, s3=0.f;
            #pragma unroll
            for (int d = 0; d < 16; ++d){
                s0 = fmaf(ev[d], wr[d].x, s0);
                s1 = fmaf(ev[d], wr[d].y, s1);
                s2 = fmaf(ev[d], wr[d].z, s2);
                s3 = fmaf(ev[d], wr[d].w, s3);
            }
            #pragma unroll
            for (int m = 8; m <= 32; m <<= 1){
                s0 += __shfl_xor(s0, m); s1 += __shfl_xor(s1, m);
                s2 += __shfl_xor(s2, m); s3 += __shfl_xor(s3, m);
            }
            if (owner){
                float4 r;
                r.x = fmaxf(us.x + s0 + bb.x, 0.f);
                r.y = fmaxf(us.y + s1 + bb.y, 0.f);
                r.z = fmaxf(us.z + s2 + bb.z, 0.f);
                r.w = fmaxf(us.w + s3 + bb.w, 0.f);
                *(float4*)&Vbuf[cur^1][p][4*k4] = r;
            }
        }
        __syncthreads();
        cur ^= 1;
    }

    // ---- final transform (root edge) + score ----
    {
        int rn = meta[g*(NND+1) + L];           // path[L-1] (= 127)
        int er = edges[rn];
        const float* Wp = EW + (size_t)er*(DD*DD) + (size_t)d0*DD + 4*k4;
        float4 wr[16];
        #pragma unroll
        for (int d = 0; d < 16; ++d) wr[d] = *(const float4*)&Wp[d*DD];
        float4 bb = *(const float4*)&EB[(size_t)er*DD + 4*k4];
        float4 sw = *(const float4*)&SEW[4*k4];
        #pragma unroll 4
        for (int p = 0; p < CH2; ++p){
            float ev[16];
            #pragma unroll
            for (int j = 0; j < 4; ++j){
                float4 x = *(const float4*)&Vbuf[cur][p][d0 + 4*j];
                ev[4*j+0]=x.x; ev[4*j+1]=x.y; ev[4*j+2]=x.z; ev[4*j+3]=x.w;
            }
            float s0=0.f, s1=0.f, s2=0.f, s3=0.f;
            #pragma unroll
            for (int d = 0; d < 16; ++d){
                s0 = fmaf(ev[d], wr[d].x, s0);
                s1 = fmaf(ev[d], wr[d].y, s1);
                s2 = fmaf(ev[d], wr[d].z, s2);
                s3 = fmaf(ev[d], wr[d].w, s3);
            }
            #pragma unroll
            for (int m = 8; m <= 32; m <<= 1){
                s0 += __shfl_xor(s0, m); s1 += __shfl_xor(s1, m);
                s2 += __shfl_xor(s2, m); s3 += __shfl_xor(s3, m);
            }
            if (owner){
                float part = (s0 + bb.x) * sw.x + (s1 + bb.y) * sw.y
                           + (s2 + bb.z) * sw.z + (s3 + bb.w) * sw.w;
                part += __shfl_xor(part, 1);
                part += __shfl_xor(part, 2);
                part += __shfl_xor(part, 4);
                if (l == 0) red[p][w] = part;
            }
        }
        __syncthreads();
        if (t < CH2)
            outp[g*DD + eBase + t] = dscore[0] + red[t][0] + red[t][1] + red[t][2] + red[t][3];
    }
}

extern "C" void kernel_launch(void* const* d_in, const int* in_sizes, int n_in,
                              void* d_out, int out_size, void* d_ws, size_t ws_size,
                              hipStream_t stream)
{
    const int*   data   = (const int*)d_in[0];
    /* d_in[1] = types, unused (single data_type) */
    const int*   graphs = (const int*)d_in[2];
    const int*   edges  = (const int*)d_in[3];
    const int*   posArr = (const int*)d_in[4];
    const float* vecs   = (const float*)d_in[5];
    const float* dw     = (const float*)d_in[6];
    const float* db     = (const float*)d_in[7];
    const float* ew     = (const float*)d_in[8];
    const float* eb     = (const float*)d_in[9];
    const float* sew    = (const float*)d_in[10];
    const float* sdw    = (const float*)d_in[11];
    const float* sb     = (const float*)d_in[12];

    char* ws = (char*)d_ws;
    float* base   = (float*)(ws);                               // 64 KB
    float* vposG  = (float*)(ws + 65536);                       // 4 KB
    float* uG     = (float*)(ws + 69632);                       // 512 KB
    float* dscore = (float*)(ws + 593920);                      // 1 f32
    int*   meta   = (int*)  (ws + 594176);                      // 8*129 ints

    float* outp = (float*)d_out;

    k_tree2 <<<GG, 1024, 0, stream>>>(data, graphs, edges, posArr, vecs, dw, db,
                                      sdw, sb, ew, eb, base, dscore, vposG, uG, meta);
    k_chain2<<<GG*(EDGEN/CH2), 256, 0, stream>>>(edges, ew, eb, sew, vposG, uG,
                                                 meta, dscore, outp);
}

// Round 4
// 408.506 us; speedup vs baseline: 1.2886x; 1.2886x over previous
//
#include <hip/hip_runtime.h>
#include <stdint.h>

// Net_49177375539428: recursive tree-NN scorer, all-fp32. 4-kernel version.
//   k_base : tiled LDS GEMM. 8 blocks x 256 thr; block b owns cols
//            [16b,16b+16): dw slice staged in LDS once, 8 tiles of 16
//            vecs-rows staged in LDS, thread = (node,col). Same 4-split
//            accumulator order as before. (Old version: 2 waves/CU chasing
//            300 strided dw loads -> latency-bound, est. 60-100 us.)
//   k_tree : level-parallel (round-2 structure) + DUAL-NODE GEMV from
//            round 3 (validated): each wave takes nodes q,q+16 of a level,
//            two independent W streams force ~2x outstanding loads.
//            Also computes dscore (g==0) from base[pos] readback.
//   k_step0: one block per edge-type e: W[e] streamed once, reused across
//            all 8 graphs (bit-identical to round 2).
//   k_steps: path chain, 16 e-rows/block, W for step s+1 prefetched into
//            a ping-pong register buffer during step s compute (static
//            two-step unroll, no dynamic reg indexing).

#define NND 128
#define DD  128
#define GG  8
#define VD  300
#define EDGEN 128
#define CH2 16         // e-rows per k_steps block

typedef unsigned int u32;

#define F_POS  (1<<16)
#define F_PATH (1<<17)

// ---------------- K1: base embeddings (tiled LDS GEMM) ----------------
__global__ void __launch_bounds__(256) k_base(
        const int* __restrict__ data, const float* __restrict__ vecs,
        const float* __restrict__ dw, const float* __restrict__ db,
        float* __restrict__ base)
{
    __shared__ __align__(16) float wcol[VD][16];     // 19200 B
    __shared__ __align__(16) float rows[16][VD];     // 19200 B
    int b = blockIdx.x, t = threadIdx.x;
    int cb = b * 16;
    for (int i = t; i < VD*16; i += 256){
        int d = i >> 4, c = i & 15;
        wcol[d][c] = dw[d*DD + cb + c];
    }
    int ci = t & 15, ni = t >> 4;
    float bias = db[cb + ci];
    for (int tile = 0; tile < 8; ++tile){
        __syncthreads();                             // rows reuse fence
        for (int i = t; i < 16*75; i += 256){        // 75 float4 per row
            int r = i / 75, e = i - r*75;
            ((float4*)&rows[r][0])[e] =
                ((const float4*)&vecs[(size_t)data[tile*16 + r]*VD])[e];
        }
        __syncthreads();
        const float* rb = &rows[ni][0];
        float a0 = bias, a1 = 0.f, a2 = 0.f, a3 = 0.f;
        for (int d = 0; d < VD; d += 4){
            a0 = fmaf(rb[d+0], wcol[d+0][ci], a0);
            a1 = fmaf(rb[d+1], wcol[d+1][ci], a1);
            a2 = fmaf(rb[d+2], wcol[d+2][ci], a2);
            a3 = fmaf(rb[d+3], wcol[d+3][ci], a3);
        }
        base[(tile*16 + ni)*DD + cb + ci] = (a0 + a1) + (a2 + a3);
    }
}

// ---------------- K2: level-parallel tree sweep (+dscore) ----------------
__global__ void __launch_bounds__(1024, 1) k_tree(
        const int* __restrict__ graphs, const int* __restrict__ edges,
        const int* __restrict__ posArr, const float* __restrict__ EW,
        const float* __restrict__ EB,   const float* __restrict__ base,
        const float* __restrict__ sdw,  const float* __restrict__ sb,
        float* __restrict__ dscore,
        float* __restrict__ vposG, float* __restrict__ uG, int* __restrict__ meta)
{
    __shared__ __align__(16) float contrib[NND-1][DD];   // 63.5 KB, nodes 0..126
    __shared__ int par_s[NND], eid_s[NND], flg_s[NND];
    __shared__ int ccnt[NND], cstart[NND], cidx[NND];
    __shared__ int dep[NND], anc[NND], lcnt[NND], lstart[NND], order[NND];
    __shared__ int maxD_s;

    int g = blockIdx.x, t = threadIdx.x;

    // ---- phase 0 (g==0 only): dscore from base[pos] readback ----
    if (g == 0){
        int p = posArr[0];
        float* red = &contrib[0][0];                 // scratch, rewritten later
        if (t < DD) red[t] = base[p*DD + t] * sdw[t];
        __syncthreads();
        for (int o = 64; o > 0; o >>= 1){ if (t < o) red[t] += red[t+o]; __syncthreads(); }
        if (t == 0) dscore[0] = sb[0] + red[0];
        __syncthreads();
    }

    // ---- phase 1: load graph structure ----
    if (t < NND){
        par_s[t] = (t < NND-1) ? (t + graphs[g*NND + t]) : (NND-1);  // root self-parent
        eid_s[t] = edges[t];
        flg_s[t] = 0;
        ccnt[t]  = 0;
        lcnt[t]  = 0;
    }
    if (t == 0) maxD_s = 0;
    __syncthreads();

    // ---- phase 2: child counts, sibling slots, depth init, path walk ----
    int mySlot = 0;
    if (t < NND-1){
        int p = par_s[t];
        atomicAdd(&ccnt[p], 1);
        for (int c = 0; c < t; ++c) mySlot += (par_s[c] == p);  // ascending order
    }
    if (t < NND){
        dep[t] = (t < NND-1) ? 1 : 0;
        anc[t] = par_s[t];
    }
    if (t == 0){
        int p = posArr[0];
        flg_s[p] |= F_POS;
        int c = par_s[p], s = 0;
        for (;;){
            flg_s[c] |= F_PATH | (s << 24);
            meta[g*(NND+1) + 1 + s] = c;
            ++s;
            if (c == NND-1) break;
            c = par_s[c];
        }
        meta[g*(NND+1)] = s;                        // path length L
    }
    __syncthreads();

    // ---- phase 3: child list offsets ----
    if (t < NND){
        int s = 0;
        for (int p = 0; p < t; ++p) s += ccnt[p];
        cstart[t] = s;
    }
    __syncthreads();
    if (t < NND-1) cidx[cstart[par_s[t]] + mySlot] = t;

    // ---- phase 4: depth via pointer jumping ----
    for (int k = 0; k < 7; ++k){
        int d2 = 0, a2 = 0;
        if (t < NND){ d2 = dep[t] + dep[anc[t]]; a2 = anc[anc[t]]; }
        __syncthreads();
        if (t < NND){ dep[t] = d2; anc[t] = a2; }
        __syncthreads();
    }
    if (t < NND) atomicMax(&maxD_s, dep[t]);
    if (t < NND) atomicAdd(&lcnt[dep[t]], 1);
    __syncthreads();

    // ---- phase 5: bucket nodes by depth ----
    if (t < NND){
        int s = 0;
        for (int d2 = 0; d2 < t; ++d2) s += lcnt[d2];
        lstart[t] = s;
    }
    __syncthreads();
    if (t < NND){
        int d2 = dep[t], s = 0;
        for (int c = 0; c < t; ++c) s += (dep[c] == d2);
        order[lstart[d2] + s] = t;
    }
    __syncthreads();

    // ---- main: rounds from deepest depth up to root, 2 nodes per wave ----
    int w = t >> 6, l = t & 63;
    int c0 = 2*l;                       // gather mapping: 2 cols/lane
    int li = l & 31, hl = l >> 5;       // GEMV mapping: 4 cols x half-d
    int c4 = 4*li, dbase = 64*hl;
    int maxD = maxD_s;

    // gather + classify; stage emb in contrib[n] if plain-GEMV node
    auto prep = [&](int n)->bool{
        float2 bse = *(const float2*)&base[n*DD + c0];
        float e0 = bse.x, e1 = bse.y;
        int cs = cstart[n], cc = ccnt[n];
        for (int j = 0; j < cc; ++j){
            int c = cidx[cs + j];
            if (!(flg_s[c] & (F_POS | F_PATH))){
                float2 cv = *(const float2*)&contrib[c][c0];
                e0 += cv.x; e1 += cv.y;
            }
        }
        int f = flg_s[n];
        if (f & F_POS){
            if (cc){ e0 = fmaxf(e0, 0.f); e1 = fmaxf(e1, 0.f); }
            *(float2*)&vposG[g*DD + c0] = make_float2(e0, e1);
            return false;
        }
        if (f & F_PATH){
            int slot = ((u32)f) >> 24;
            *(float2*)&uG[((size_t)g*NND + slot)*DD + c0] = make_float2(e0, e1);  // pre-relu
            return false;
        }
        if (cc){ e0 = fmaxf(e0, 0.f); e1 = fmaxf(e1, 0.f); }
        *(float2*)&contrib[n][c0] = make_float2(e0, e1);       // stage emb
        return true;
    };

    auto gemv1 = [&](int n){
        int e = eid_s[n];
        const float* Wp = EW + (size_t)e*(DD*DD) + (size_t)dbase*DD + c4;
        const float* xr = &contrib[n][dbase];
        float4 A[8], B[8];
        float s0=0.f, s1=0.f, s2=0.f, s3=0.f;
        #define LW(buf, gi) { _Pragma("unroll") \
            for (int j2 = 0; j2 < 8; ++j2) \
                buf[j2] = *(const float4*)&Wp[(size_t)((gi)*8 + j2)*DD]; }
        #define CP(buf, gi) { _Pragma("unroll") \
            for (int j2 = 0; j2 < 8; ++j2){ \
                float x = xr[(gi)*8 + j2]; \
                s0 = fmaf(x, buf[j2].x, s0); s1 = fmaf(x, buf[j2].y, s1); \
                s2 = fmaf(x, buf[j2].z, s2); s3 = fmaf(x, buf[j2].w, s3); } }
        LW(A,0); LW(B,1);
        CP(A,0); LW(A,2);
        CP(B,1); LW(B,3);
        CP(A,2); LW(A,4);
        CP(B,3); LW(B,5);
        CP(A,4); LW(A,6);
        CP(B,5); LW(B,7);
        CP(A,6);
        CP(B,7);
        #undef LW
        #undef CP
        s0 += __shfl_xor(s0, 32); s1 += __shfl_xor(s1, 32);
        s2 += __shfl_xor(s2, 32); s3 += __shfl_xor(s3, 32);
        if (hl == 0){
            float4 bb = *(const float4*)&EB[(size_t)e*DD + c4];
            *(float4*)&contrib[n][c4] =
                make_float4(s0 + bb.x, s1 + bb.y, s2 + bb.z, s3 + bb.w);
        }
    };

    auto gemv2 = [&](int n1, int n2){
        int ea = eid_s[n1], eb = eid_s[n2];
        const float* W1 = EW + (size_t)ea*(DD*DD) + (size_t)dbase*DD + c4;
        const float* W2 = EW + (size_t)eb*(DD*DD) + (size_t)dbase*DD + c4;
        const float* x1 = &contrib[n1][dbase];
        const float* x2 = &contrib[n2][dbase];
        float4 A[8], B[8];
        float a0=0.f,a1=0.f,a2=0.f,a3=0.f, b0=0.f,b1=0.f,b2=0.f,b3=0.f;
        #define LW1(gi) { _Pragma("unroll") \
            for (int j2 = 0; j2 < 8; ++j2) \
                A[j2] = *(const float4*)&W1[(size_t)((gi)*8 + j2)*DD]; }
        #define LW2(gi) { _Pragma("unroll") \
            for (int j2 = 0; j2 < 8; ++j2) \
                B[j2] = *(const float4*)&W2[(size_t)((gi)*8 + j2)*DD]; }
        #define CP1(gi) { _Pragma("unroll") \
            for (int j2 = 0; j2 < 8; ++j2){ \
                float x = x1[(gi)*8 + j2]; \
                a0 = fmaf(x, A[j2].x, a0); a1 = fmaf(x, A[j2].y, a1); \
                a2 = fmaf(x, A[j2].z, a2); a3 = fmaf(x, A[j2].w, a3); } }
        #define CP2(gi) { _Pragma("unroll") \
            for (int j2 = 0; j2 < 8; ++j2){ \
                float x = x2[(gi)*8 + j2]; \
                b0 = fmaf(x, B[j2].x, b0); b1 = fmaf(x, B[j2].y, b1); \
                b2 = fmaf(x, B[j2].z, b2); b3 = fmaf(x, B[j2].w, b3); } }
        LW1(0); LW2(0);
        CP1(0); LW1(1);
        CP2(0); LW2(1);
        CP1(1); LW1(2);
        CP2(1); LW2(2);
        CP1(2); LW1(3);
        CP2(2); LW2(3);
        CP1(3); LW1(4);
        CP2(3); LW2(4);
        CP1(4); LW1(5);
        CP2(4); LW2(5);
        CP1(5); LW1(6);
        CP2(5); LW2(6);
        CP1(6); LW1(7);
        CP2(6); LW2(7);
        CP1(7);
        CP2(7);
        #undef LW1
        #undef LW2
        #undef CP1
        #undef CP2
        a0 += __shfl_xor(a0, 32); a1 += __shfl_xor(a1, 32);
        a2 += __shfl_xor(a2, 32); a3 += __shfl_xor(a3, 32);
        b0 += __shfl_xor(b0, 32); b1 += __shfl_xor(b1, 32);
        b2 += __shfl_xor(b2, 32); b3 += __shfl_xor(b3, 32);
        if (hl == 0){
            float4 ba = *(const float4*)&EB[(size_t)ea*DD + c4];
            float4 bb = *(const float4*)&EB[(size_t)eb*DD + c4];
            *(float4*)&contrib[n1][c4] =
                make_float4(a0 + ba.x, a1 + ba.y, a2 + ba.z, a3 + ba.w);
            *(float4*)&contrib[n2][c4] =
                make_float4(b0 + bb.x, b1 + bb.y, b2 + bb.z, b3 + bb.w);
        }
    };

    for (int d = maxD; d >= 0; --d){
        int lo = lstart[d], cnt = lcnt[d];
        for (int q = w; q < cnt; q += 32){
            int n1 = order[lo + q];
            int n2 = (q + 16 < cnt) ? order[lo + q + 16] : -1;
            bool p1 = prep(n1);
            bool p2 = (n2 >= 0) ? prep(n2) : false;
            asm volatile("s_waitcnt lgkmcnt(0)" ::: "memory");   // staged emb RAW
            if (p1 && p2)      gemv2(n1, n2);
            else { if (p1) gemv1(n1);
                   if (p2) gemv1(n2); }
        }
        __syncthreads();
    }
}

// ---------------- K3a: step 0, batched over graphs ----------------
__global__ void __launch_bounds__(256, 1) k_step0(
        const float* __restrict__ EW, const float* __restrict__ EB,
        const float* __restrict__ vposG, const float* __restrict__ uG,
        float* __restrict__ V0)
{
    __shared__ __align__(16) float vpos_s[GG][DD];
    int e = blockIdx.x, t = threadIdx.x, l = t & 63, w = t >> 6;
    {
        int idx = t;                                 // GG*DD/4 == 256 exactly
        ((float4*)vpos_s)[idx] = ((const float4*)vposG)[idx];
    }
    __syncthreads();
    int k4 = w*8 + (l & 7);
    int d0 = (l >> 3) * 16;
    bool owner = ((l >> 3) == 0);
    const float* Wp = EW + (size_t)e*(DD*DD) + (size_t)d0*DD + 4*k4;
    float4 wr[16];
    #pragma unroll
    for (int d = 0; d < 16; ++d) wr[d] = *(const float4*)&Wp[d*DD];
    float4 bb = *(const float4*)&EB[(size_t)e*DD + 4*k4];
    for (int g = 0; g < GG; ++g){
        float s0=0.f, s1=0.f, s2=0.f, s3=0.f;
        #pragma unroll
        for (int d = 0; d < 16; ++d){
            float x = vpos_s[g][d0 + d];
            s0 = fmaf(x, wr[d].x, s0);
            s1 = fmaf(x, wr[d].y, s1);
            s2 = fmaf(x, wr[d].z, s2);
            s3 = fmaf(x, wr[d].w, s3);
        }
        #pragma unroll
        for (int m = 8; m <= 32; m <<= 1){
            s0 += __shfl_xor(s0, m); s1 += __shfl_xor(s1, m);
            s2 += __shfl_xor(s2, m); s3 += __shfl_xor(s3, m);
        }
        if (owner){
            float4 u0 = *(const float4*)&uG[(size_t)g*NND*DD + 4*k4];
            float4 r;
            r.x = fmaxf(u0.x + s0 + bb.x, 0.f);
            r.y = fmaxf(u0.y + s1 + bb.y, 0.f);
            r.z = fmaxf(u0.z + s2 + bb.z, 0.f);
            r.w = fmaxf(u0.w + s3 + bb.w, 0.f);
            *(float4*)&V0[((size_t)g*EDGEN + e)*DD + 4*k4] = r;
        }
    }
}

// ---------------- K3b: path chains, W-prefetch pipelined ----------------
__global__ void __launch_bounds__(256, 1) k_steps(
        const int* __restrict__ edges,
        const float* __restrict__ EW, const float* __restrict__ EB,
        const float* __restrict__ SEW,
        const float* __restrict__ uG, const float* __restrict__ V0,
        const int* __restrict__ meta, const float* __restrict__ dscore,
        float* __restrict__ outp)
{
    __shared__ __align__(16) float Vbuf[2][CH2][DD];
    __shared__ float red[CH2][4];
    int g = blockIdx.x >> 3, chunk = blockIdx.x & 7;
    int t = threadIdx.x, l = t & 63, w = t >> 6;
    int k4 = w*8 + (l & 7);
    int d0 = (l >> 3) * 16;
    bool owner = ((l >> 3) == 0);
    int eBase = chunk * CH2;
    int L = meta[g*(NND+1)];

    // load this block's 16 step-0 rows
    for (int idx = t; idx < CH2*DD/4; idx += 256)
        ((float4*)&Vbuf[0][0][0])[idx] =
            ((const float4*)&V0[((size_t)g*EDGEN + eBase)*DD])[idx];
    __syncthreads();

    int cur = 0;

    auto loadW = [&](int s2, float4 (&wr)[16]){
        int pn = meta[g*(NND+1) + s2];
        int ej = edges[pn];
        const float* Wp = EW + (size_t)ej*(DD*DD) + (size_t)d0*DD + 4*k4;
        #pragma unroll
        for (int d = 0; d < 16; ++d) wr[d] = *(const float4*)&Wp[d*DD];
    };

    auto stepC = [&](int s2, float4 (&wr)[16]){
        int pn = meta[g*(NND+1) + s2];
        int ej = edges[pn];
        float4 us = *(const float4*)&uG[((size_t)g*NND + s2)*DD + 4*k4];
        float4 bb = *(const float4*)&EB[(size_t)ej*DD + 4*k4];
        #pragma unroll 4
        for (int p = 0; p < CH2; ++p){
            float ev[16];
            #pragma unroll
            for (int j = 0; j < 4; ++j){
                float4 x = *(const float4*)&Vbuf[cur][p][d0 + 4*j];
                ev[4*j+0]=x.x; ev[4*j+1]=x.y; ev[4*j+2]=x.z; ev[4*j+3]=x.w;
            }
            float s0=0.f, s1=0.f, s2b=0.f, s3=0.f;
            #pragma unroll
            for (int d = 0; d < 16; ++d){
                s0  = fmaf(ev[d], wr[d].x, s0);
                s1  = fmaf(ev[d], wr[d].y, s1);
                s2b = fmaf(ev[d], wr[d].z, s2b);
                s3  = fmaf(ev[d], wr[d].w, s3);
            }
            #pragma unroll
            for (int m = 8; m <= 32; m <<= 1){
                s0 += __shfl_xor(s0, m); s1 += __shfl_xor(s1, m);
                s2b += __shfl_xor(s2b, m); s3 += __shfl_xor(s3, m);
            }
            if (owner){
                float4 r;
                r.x = fmaxf(us.x + s0  + bb.x, 0.f);
                r.y = fmaxf(us.y + s1  + bb.y, 0.f);
                r.z = fmaxf(us.z + s2b + bb.z, 0.f);
                r.w = fmaxf(us.w + s3  + bb.w, 0.f);
                *(float4*)&Vbuf[cur^1][p][4*k4] = r;
            }
        }
        __syncthreads();
        cur ^= 1;
    };

    // ---- shared steps 1..L-1, ping-pong W prefetch (static 2-step unroll) ----
    if (L > 1){
        float4 wrA[16], wrB[16];
        loadW(1, wrA);
        int s = 1;
        for (;;){
            if (s + 1 < L) loadW(s + 1, wrB);   // prefetch overlaps stepC(wrA)
            stepC(s, wrA);
            ++s; if (s >= L) break;
            if (s + 1 < L) loadW(s + 1, wrA);   // prefetch overlaps stepC(wrB)
            stepC(s, wrB);
            ++s; if (s >= L) break;
        }
    }

    // ---- final transform (root edge) + score ----
    {
        int rn = meta[g*(NND+1) + L];           // path[L-1] (= 127)
        int er = edges[rn];
        const float* Wp = EW + (size_t)er*(DD*DD) + (size_t)d0*DD + 4*k4;
        float4 wr[16];
        #pragma unroll
        for (int d = 0; d < 16; ++d) wr[d] = *(const float4*)&Wp[d*DD];
        float4 bb = *(const float4*)&EB[(size_t)er*DD + 4*k4];
        float4 sw = *(const float4*)&SEW[4*k4];
        #pragma unroll 4
        for (int p = 0; p < CH2; ++p){
            float ev[16];
            #pragma unroll
            for (int j = 0; j < 4; ++j){
                float4 x = *(const float4*)&Vbuf[cur][p][d0 + 4*j];
                ev[4*j+0]=x.x; ev[4*j+1]=x.y; ev[4*j+2]=x.z; ev[4*j+3]=x.w;
            }
            float s0=0.f, s1=0.f, s2=0.f, s3=0.f;
            #pragma unroll
            for (int d = 0; d < 16; ++d){
                s0 = fmaf(ev[d], wr[d].x, s0);
                s1 = fmaf(ev[d], wr[d].y, s1);
                s2 = fmaf(ev[d], wr[d].z, s2);
                s3 = fmaf(ev[d], wr[d].w, s3);
            }
            #pragma unroll
            for (int m = 8; m <= 32; m <<= 1){
                s0 += __shfl_xor(s0, m); s1 += __shfl_xor(s1, m);
                s2 += __shfl_xor(s2, m); s3 += __shfl_xor(s3, m);
            }
            if (owner){
                float part = (s0 + bb.x) * sw.x + (s1 + bb.y) * sw.y
                           + (s2 + bb.z) * sw.z + (s3 + bb.w) * sw.w;
                part += __shfl_xor(part, 1);
                part += __shfl_xor(part, 2);
                part += __shfl_xor(part, 4);
                if (l == 0) red[p][w] = part;
            }
        }
        __syncthreads();
        if (t < CH2)
            outp[g*DD + eBase + t] = dscore[0] + red[t][0] + red[t][1] + red[t][2] + red[t][3];
    }
}

extern "C" void kernel_launch(void* const* d_in, const int* in_sizes, int n_in,
                              void* d_out, int out_size, void* d_ws, size_t ws_size,
                              hipStream_t stream)
{
    const int*   data   = (const int*)d_in[0];
    /* d_in[1] = types, unused (single data_type) */
    const int*   graphs = (const int*)d_in[2];
    const int*   edges  = (const int*)d_in[3];
    const int*   posArr = (const int*)d_in[4];
    const float* vecs   = (const float*)d_in[5];
    const float* dw     = (const float*)d_in[6];
    const float* db     = (const float*)d_in[7];
    const float* ew     = (const float*)d_in[8];
    const float* eb     = (const float*)d_in[9];
    const float* sew    = (const float*)d_in[10];
    const float* sdw    = (const float*)d_in[11];
    const float* sb     = (const float*)d_in[12];

    char* ws = (char*)d_ws;
    float* base   = (float*)(ws);                               // 64 KB
    float* vposG  = (float*)(ws + 65536);                       // 4 KB
    float* uG     = (float*)(ws + 69632);                       // 512 KB
    float* dscore = (float*)(ws + 593920);                      // 1 f32
    int*   meta   = (int*)  (ws + 594176);                      // 8*129 ints
    float* V0     = (float*)(ws + 598528);                      // 512 KB

    float* outp = (float*)d_out;

    k_base <<<8, 256, 0, stream>>>(data, vecs, dw, db, base);
    k_tree <<<GG, 1024, 0, stream>>>(graphs, edges, posArr, ew, eb, base,
                                     sdw, sb, dscore, vposG, uG, meta);
    k_step0<<<EDGEN, 256, 0, stream>>>(ew, eb, vposG, uG, V0);
    k_steps<<<GG*(EDGEN/CH2), 256, 0, stream>>>(edges, ew, eb, sew, uG, V0,
                                                meta, dscore, outp);
}

// Round 5
// 341.206 us; speedup vs baseline: 1.5428x; 1.1972x over previous
//
#include <hip/hip_runtime.h>
#include <stdint.h>

// Net_49177375539428: recursive tree-NN scorer, all-fp32.
//   k_base : base[n,:] = vecs[data[n]] @ Wd + bd ; d_score at n==pos.
//            (round-2 version, verbatim)
//   k_tree : DATAFLOW rewrite. 8 blocks x 1024 thr (16 waves). No per-level
//            barriers: per-node LDS child-counters + a monotonic LDS work
//            queue. Leaves enqueued at setup; a wave claims a slot, spins
//            till filled, runs the EXACT round-2 prep+gemv1 (bit-identical
//            math), then decrements its parent's counter and enqueues the
//            parent when last. Nodes start the moment children finish ->
//            continuous overlap of W streams; target the ~51 us per-CU
//            port floor (round-2 level-barrier version: 106 us).
//   k_step0: one block per edge-type e: W[e] streamed once, reused across
//            all 8 graphs (round-2 version, verbatim).
//   k_steps: path chain, 16 e-rows per block (round-2 version, verbatim).

#define NND 128
#define DD  128
#define GG  8
#define VD  300
#define EDGEN 128
#define CH2 16         // e-rows per k_steps block

typedef unsigned int u32;

#define F_POS  (1<<16)
#define F_PATH (1<<17)

// ---------------- K1: base embeddings + d_score ----------------
__global__ void __launch_bounds__(128) k_base(
        const int* __restrict__ data, const int* __restrict__ posArr,
        const float* __restrict__ vecs, const float* __restrict__ dw,
        const float* __restrict__ db,   const float* __restrict__ sdw,
        const float* __restrict__ sb,
        float* __restrict__ base, float* __restrict__ dscore)
{
    __shared__ __align__(16) float row[VD];
    __shared__ float red[DD];
    int n = blockIdx.x, t = threadIdx.x;
    int id = data[n];
    const float4* vp = (const float4*)(vecs + (size_t)id * VD);  // 1200B rows
    for (int i = t; i < VD/4; i += 128) ((float4*)row)[i] = vp[i];
    __syncthreads();
    float a0 = db[t], a1 = 0.f, a2 = 0.f, a3 = 0.f;
    for (int d = 0; d < VD; d += 4){
        a0 = fmaf(row[d+0], dw[(d+0)*DD + t], a0);
        a1 = fmaf(row[d+1], dw[(d+1)*DD + t], a1);
        a2 = fmaf(row[d+2], dw[(d+2)*DD + t], a2);
        a3 = fmaf(row[d+3], dw[(d+3)*DD + t], a3);
    }
    float acc = (a0 + a1) + (a2 + a3);
    base[n*DD + t] = acc;
    if (n == posArr[0]){
        red[t] = acc * sdw[t];
        __syncthreads();
        for (int o = 64; o > 0; o >>= 1){ if (t < o) red[t] += red[t+o]; __syncthreads(); }
        if (t == 0) dscore[0] = sb[0] + red[0];
    }
}

// ---------------- K2: dataflow tree sweep ----------------
__global__ void __launch_bounds__(1024, 1) k_tree(
        const int* __restrict__ graphs, const int* __restrict__ edges,
        const int* __restrict__ posArr, const float* __restrict__ EW,
        const float* __restrict__ EB,   const float* __restrict__ base,
        float* __restrict__ vposG, float* __restrict__ uG, int* __restrict__ meta)
{
    __shared__ __align__(16) float contrib[NND-1][DD];   // 63.5 KB, nodes 0..126
    __shared__ int par_s[NND], eid_s[NND], flg_s[NND];
    __shared__ int ccnt[NND], cstart[NND], cidx[NND];
    __shared__ int kcnt[NND];          // remaining-children counters
    __shared__ int queue[NND];         // monotonic ready-queue (node ids)
    __shared__ int qhead, qtail;

    int g = blockIdx.x, t = threadIdx.x;

    // ---- phase 1: load graph structure, init queue ----
    if (t < NND){
        par_s[t] = (t < NND-1) ? (t + graphs[g*NND + t]) : (NND-1);  // root self-parent
        eid_s[t] = edges[t];
        flg_s[t] = 0;
        ccnt[t]  = 0;
        queue[t] = -1;
    }
    if (t == 0){ qhead = 0; qtail = 0; }
    __syncthreads();

    // ---- phase 2: child counts, sibling slots, path walk ----
    int mySlot = 0;
    if (t < NND-1){
        int p = par_s[t];
        atomicAdd(&ccnt[p], 1);
        for (int c = 0; c < t; ++c) mySlot += (par_s[c] == p);  // ascending order
    }
    if (t == 0){
        int p = posArr[0];
        flg_s[p] |= F_POS;
        int c = par_s[p], s = 0;
        for (;;){
            flg_s[c] |= F_PATH | (s << 24);
            meta[g*(NND+1) + 1 + s] = c;
            ++s;
            if (c == NND-1) break;
            c = par_s[c];
        }
        meta[g*(NND+1)] = s;                        // path length L
    }
    __syncthreads();

    // ---- phase 3: child list offsets, counters, leaf pushes ----
    if (t < NND){
        int s = 0;
        for (int p = 0; p < t; ++p) s += ccnt[p];
        cstart[t] = s;
        kcnt[t] = ccnt[t];
    }
    __syncthreads();
    if (t < NND-1) cidx[cstart[par_s[t]] + mySlot] = t;
    if (t < NND && ccnt[t] == 0){
        int slot = atomicAdd(&qtail, 1);
        queue[slot] = t;                            // leaves ready immediately
    }
    __syncthreads();

    // ---- main: dataflow loop, no barriers ----
    int l = t & 63;
    int c0 = 2*l;                       // gather mapping: 2 cols/lane
    int li = l & 31, hl = l >> 5;       // GEMV mapping: 4 cols x half-d
    int c4 = 4*li, dbase = 64*hl;

    // gather + classify; stage emb in contrib[n] if plain-GEMV node
    auto prep = [&](int n)->bool{
        float2 bse = *(const float2*)&base[n*DD + c0];
        float e0 = bse.x, e1 = bse.y;
        int cs = cstart[n], cc = ccnt[n];
        for (int j = 0; j < cc; ++j){
            int c = cidx[cs + j];
            if (!(flg_s[c] & (F_POS | F_PATH))){
                float2 cv = *(const float2*)&contrib[c][c0];
                e0 += cv.x; e1 += cv.y;
            }
        }
        int f = flg_s[n];
        if (f & F_POS){
            if (cc){ e0 = fmaxf(e0, 0.f); e1 = fmaxf(e1, 0.f); }
            *(float2*)&vposG[g*DD + c0] = make_float2(e0, e1);
            return false;
        }
        if (f & F_PATH){
            int slot = ((u32)f) >> 24;
            *(float2*)&uG[((size_t)g*NND + slot)*DD + c0] = make_float2(e0, e1);  // pre-relu
            return false;
        }
        if (cc){ e0 = fmaxf(e0, 0.f); e1 = fmaxf(e1, 0.f); }
        *(float2*)&contrib[n][c0] = make_float2(e0, e1);       // stage emb
        return true;
    };

    auto gemv1 = [&](int n){
        int e = eid_s[n];
        const float* Wp = EW + (size_t)e*(DD*DD) + (size_t)dbase*DD + c4;
        const float* xr = &contrib[n][dbase];
        float4 A[8], B[8];
        float s0=0.f, s1=0.f, s2=0.f, s3=0.f;
        #define LW(buf, gi) { _Pragma("unroll") \
            for (int j2 = 0; j2 < 8; ++j2) \
                buf[j2] = *(const float4*)&Wp[(size_t)((gi)*8 + j2)*DD]; }
        #define CP(buf, gi) { _Pragma("unroll") \
            for (int j2 = 0; j2 < 8; ++j2){ \
                float x = xr[(gi)*8 + j2]; \
                s0 = fmaf(x, buf[j2].x, s0); s1 = fmaf(x, buf[j2].y, s1); \
                s2 = fmaf(x, buf[j2].z, s2); s3 = fmaf(x, buf[j2].w, s3); } }
        LW(A,0); LW(B,1);
        CP(A,0); LW(A,2);
        CP(B,1); LW(B,3);
        CP(A,2); LW(A,4);
        CP(B,3); LW(B,5);
        CP(A,4); LW(A,6);
        CP(B,5); LW(B,7);
        CP(A,6);
        CP(B,7);
        #undef LW
        #undef CP
        s0 += __shfl_xor(s0, 32); s1 += __shfl_xor(s1, 32);
        s2 += __shfl_xor(s2, 32); s3 += __shfl_xor(s3, 32);
        if (hl == 0){
            float4 bb = *(const float4*)&EB[(size_t)e*DD + c4];
            *(float4*)&contrib[n][c4] =
                make_float4(s0 + bb.x, s1 + bb.y, s2 + bb.z, s3 + bb.w);
        }
    };

    for (;;){
        int idx = 0;
        if (l == 0) idx = atomicAdd(&qhead, 1);     // claim a queue slot
        idx = __shfl(idx, 0);
        if (idx >= NND) break;                       // all nodes claimed
        volatile int* qp = (volatile int*)&queue[idx];
        int n;
        while ((n = *qp) < 0) ;                      // spin till slot filled
        bool doG = prep(n);
        asm volatile("s_waitcnt lgkmcnt(0)" ::: "memory");   // staged emb RAW
        if (doG) gemv1(n);
        asm volatile("s_waitcnt lgkmcnt(0)" ::: "memory");   // y write complete
        if (l == 0 && n != NND-1){
            int p = par_s[n];
            int old = atomicSub(&kcnt[p], 1);
            if (old == 1){                           // last child -> parent ready
                int slot = atomicAdd(&qtail, 1);
                queue[slot] = p;
            }
        }
    }
}

// ---------------- K3a: step 0, batched over graphs ----------------
__global__ void __launch_bounds__(256, 1) k_step0(
        const float* __restrict__ EW, const float* __restrict__ EB,
        const float* __restrict__ vposG, const float* __restrict__ uG,
        float* __restrict__ V0)
{
    __shared__ __align__(16) float vpos_s[GG][DD];
    int e = blockIdx.x, t = threadIdx.x, l = t & 63, w = t >> 6;
    {
        int idx = t;                                 // GG*DD/4 == 256 exactly
        ((float4*)vpos_s)[idx] = ((const float4*)vposG)[idx];
    }
    __syncthreads();
    int k4 = w*8 + (l & 7);
    int d0 = (l >> 3) * 16;
    bool owner = ((l >> 3) == 0);
    const float* Wp = EW + (size_t)e*(DD*DD) + (size_t)d0*DD + 4*k4;
    float4 wr[16];
    #pragma unroll
    for (int d = 0; d < 16; ++d) wr[d] = *(const float4*)&Wp[d*DD];
    float4 bb = *(const float4*)&EB[(size_t)e*DD + 4*k4];
    for (int g = 0; g < GG; ++g){
        float s0=0.f, s1=0.f, s2=0.f, s3=0.f;
        #pragma unroll
        for (int d = 0; d < 16; ++d){
            float x = vpos_s[g][d0 + d];
            s0 = fmaf(x, wr[d].x, s0);
            s1 = fmaf(x, wr[d].y, s1);
            s2 = fmaf(x, wr[d].z, s2);
            s3 = fmaf(x, wr[d].w, s3);
        }
        #pragma unroll
        for (int m = 8; m <= 32; m <<= 1){
            s0 += __shfl_xor(s0, m); s1 += __shfl_xor(s1, m);
            s2 += __shfl_xor(s2, m); s3 += __shfl_xor(s3, m);
        }
        if (owner){
            float4 u0 = *(const float4*)&uG[(size_t)g*NND*DD + 4*k4];
            float4 r;
            r.x = fmaxf(u0.x + s0 + bb.x, 0.f);
            r.y = fmaxf(u0.y + s1 + bb.y, 0.f);
            r.z = fmaxf(u0.z + s2 + bb.z, 0.f);
            r.w = fmaxf(u0.w + s3 + bb.w, 0.f);
            *(float4*)&V0[((size_t)g*EDGEN + e)*DD + 4*k4] = r;
        }
    }
}

// ---------------- K3b: path chains, 16 e-rows per block ----------------
__global__ void __launch_bounds__(256, 1) k_steps(
        const int* __restrict__ edges,
        const float* __restrict__ EW, const float* __restrict__ EB,
        const float* __restrict__ SEW,
        const float* __restrict__ uG, const float* __restrict__ V0,
        const int* __restrict__ meta, const float* __restrict__ dscore,
        float* __restrict__ outp)
{
    __shared__ __align__(16) float Vbuf[2][CH2][DD];
    __shared__ float red[CH2][4];
    int g = blockIdx.x >> 3, chunk = blockIdx.x & 7;
    int t = threadIdx.x, l = t & 63, w = t >> 6;
    int k4 = w*8 + (l & 7);
    int d0 = (l >> 3) * 16;
    bool owner = ((l >> 3) == 0);
    int eBase = chunk * CH2;
    int L = meta[g*(NND+1)];

    // load this block's 16 step-0 rows
    for (int idx = t; idx < CH2*DD/4; idx += 256)
        ((float4*)&Vbuf[0][0][0])[idx] =
            ((const float4*)&V0[((size_t)g*EDGEN + eBase)*DD])[idx];
    __syncthreads();

    // ---- shared steps 1..L-1: one W per step, reused across CH2 e-rows ----
    int cur = 0;
    for (int s = 1; s < L; ++s){
        int pn = meta[g*(NND+1) + s];           // path[s-1]
        int ej = edges[pn];
        const float* Wp = EW + (size_t)ej*(DD*DD) + (size_t)d0*DD + 4*k4;
        float4 wr[16];
        #pragma unroll
        for (int d = 0; d < 16; ++d) wr[d] = *(const float4*)&Wp[d*DD];
        float4 us = *(const float4*)&uG[((size_t)g*NND + s)*DD + 4*k4];
        float4 bb = *(const float4*)&EB[(size_t)ej*DD + 4*k4];
        #pragma unroll 4
        for (int p = 0; p < CH2; ++p){
            float ev[16];
            #pragma unroll
            for (int j = 0; j < 4; ++j){
                float4 x = *(const float4*)&Vbuf[cur][p][d0 + 4*j];
                ev[4*j+0]=x.x; ev[4*j+1]=x.y; ev[4*j+2]=x.z; ev[4*j+3]=x.w;
            }
            float s0=0.f, s1=0.f, s2=0.f, s3=0.f;
            #pragma unroll
            for (int d = 0; d < 16; ++d){
                s0 = fmaf(ev[d], wr[d].x, s0);
                s1 = fmaf(ev[d], wr[d].y, s1);
                s2 = fmaf(ev[d], wr[d].z, s2);
                s3 = fmaf(ev[d], wr[d].w, s3);
            }
            #pragma unroll
            for (int m = 8; m <= 32; m <<= 1){
                s0 += __shfl_xor(s0, m); s1 += __shfl_xor(s1, m);
                s2 += __shfl_xor(s2, m); s3 += __shfl_xor(s3, m);
            }
            if (owner){
                float4 r;
                r.x = fmaxf(us.x + s0 + bb.x, 0.f);
                r.y = fmaxf(us.y + s1 + bb.y, 0.f);
                r.z = fmaxf(us.z + s2 + bb.z, 0.f);
                r.w = fmaxf(us.w + s3 + bb.w, 0.f);
                *(float4*)&Vbuf[cur^1][p][4*k4] = r;
            }
        }
        __syncthreads();
        cur ^= 1;
    }

    // ---- final transform (root edge) + score ----
    {
        int rn = meta[g*(NND+1) + L];           // path[L-1] (= 127)
        int er = edges[rn];
        const float* Wp = EW + (size_t)er*(DD*DD) + (size_t)d0*DD + 4*k4;
        float4 wr[16];
        #pragma unroll
        for (int d = 0; d < 16; ++d) wr[d] = *(const float4*)&Wp[d*DD];
        float4 bb = *(const float4*)&EB[(size_t)er*DD + 4*k4];
        float4 sw = *(const float4*)&SEW[4*k4];
        #pragma unroll 4
        for (int p = 0; p < CH2; ++p){
            float ev[16];
            #pragma unroll
            for (int j = 0; j < 4; ++j){
                float4 x = *(const float4*)&Vbuf[cur][p][d0 + 4*j];
                ev[4*j+0]=x.x; ev[4*j+1]=x.y; ev[4*j+2]=x.z; ev[4*j+3]=x.w;
            }
            float s0=0.f, s1=0.f, s2=0.f, s3=0.f;
            #pragma unroll
            for (int d = 0; d < 16; ++d){
                s0 = fmaf(ev[d], wr[d].x, s0);
                s1 = fmaf(ev[d], wr[d].y, s1);
                s2 = fmaf(ev[d], wr[d].z, s2);
                s3 = fmaf(ev[d], wr[d].w, s3);
            }
            #pragma unroll
            for (int m = 8; m <= 32; m <<= 1){
                s0 += __shfl_xor(s0, m); s1 += __shfl_xor(s1, m);
                s2 += __shfl_xor(s2, m); s3 += __shfl_xor(s3, m);
            }
            if (owner){
                float part = (s0 + bb.x) * sw.x + (s1 + bb.y) * sw.y
                           + (s2 + bb.z) * sw.z + (s3 + bb.w) * sw.w;
                part += __shfl_xor(part, 1);
                part += __shfl_xor(part, 2);
                part += __shfl_xor(part, 4);
                if (l == 0) red[p][w] = part;
            }
        }
        __syncthreads();
        if (t < CH2)
            outp[g*DD + eBase + t] = dscore[0] + red[t][0] + red[t][1] + red[t][2] + red[t][3];
    }
}

extern "C" void kernel_launch(void* const* d_in, const int* in_sizes, int n_in,
                              void* d_out, int out_size, void* d_ws, size_t ws_size,
                              hipStream_t stream)
{
    const int*   data   = (const int*)d_in[0];
    /* d_in[1] = types, unused (single data_type) */
    const int*   graphs = (const int*)d_in[2];
    const int*   edges  = (const int*)d_in[3];
    const int*   posArr = (const int*)d_in[4];
    const float* vecs   = (const float*)d_in[5];
    const float* dw     = (const float*)d_in[6];
    const float* db     = (const float*)d_in[7];
    const float* ew     = (const float*)d_in[8];
    const float* eb     = (const float*)d_in[9];
    const float* sew    = (const float*)d_in[10];
    const float* sdw    = (const float*)d_in[11];
    const float* sb     = (const float*)d_in[12];

    char* ws = (char*)d_ws;
    float* base   = (float*)(ws);                               // 64 KB
    float* vposG  = (float*)(ws + 65536);                       // 4 KB
    float* uG     = (float*)(ws + 69632);                       // 512 KB
    float* dscore = (float*)(ws + 593920);                      // 1 f32
    int*   meta   = (int*)  (ws + 594176);                      // 8*129 ints
    float* V0     = (float*)(ws + 598528);                      // 512 KB

    float* outp = (float*)d_out;

    k_base <<<NND, 128, 0, stream>>>(data, posArr, vecs, dw, db, sdw, sb, base, dscore);
    k_tree <<<GG, 1024, 0, stream>>>(graphs, edges, posArr, ew, eb, base, vposG, uG, meta);
    k_step0<<<EDGEN, 256, 0, stream>>>(ew, eb, vposG, uG, V0);
    k_steps<<<GG*(EDGEN/CH2), 256, 0, stream>>>(edges, ew, eb, sew, uG, V0,
                                                meta, dscore, outp);
}